// Round 4
// baseline (273.915 us; speedup 1.0000x reference)
//
#include <hip/hip_runtime.h>
#include <cstdint>

typedef unsigned short u16;
typedef unsigned int   u32;

#define DIM     128
#define TPITCH  136          // LDS W row pitch in bf16 (bank-spread)
#define BSH     8            // nodes per fine bucket = 256
#define BSIZE   256
#define NBK_MAX 512          // supports n <= 131072 at BSIZE=256
#define CHUNK   4096         // edges per L1 sort block

__device__ __forceinline__ u16 f2bf(float x) {   // fp32 -> bf16 RTNE
    u32 u = __float_as_uint(x);
    u32 r = u + 0x7FFFu + ((u >> 16) & 1u);
    return (u16)(r >> 16);
}

typedef __attribute__((ext_vector_type(8))) short bfrag;
typedef __attribute__((ext_vector_type(4))) float f32x4;
typedef __attribute__((ext_vector_type(2))) float f32x2;

// ---------------------------------------------------------------------------
// K1 (fat): blocks [0, nCntBlk) do the L1 bucket count; the rest compute
// T(bf16) = A @ W^T with mfma_f32_16x16x32_bf16 (A, W cast to bf16 in-flight).
// Each wave: 16 rows x 128 cols (8 col-tiles, 4 k-steps, 32 MFMA).
// ---------------------------------------------------------------------------
__global__ __launch_bounds__(256) void k_count_transform(
    const float* __restrict__ A, const float* __restrict__ W,
    u16* __restrict__ Tb,
    const int* __restrict__ dst, int* __restrict__ cnt,
    int n, int E, int nCntBlk, int NBK)
{
    __shared__ u16 Wb[DIM * TPITCH];   // 34816 B; count blocks reuse as hist

    if (blockIdx.x < nCntBlk) {
        int* hist = (int*)Wb;
        for (int i = threadIdx.x; i < NBK; i += 256) hist[i] = 0;
        __syncthreads();
        const int base = blockIdx.x * CHUNK;
        const int end  = min(base + CHUNK, E);
        for (int i = base + threadIdx.x; i < end; i += 256)
            atomicAdd(&hist[dst[i] >> BSH], 1);
        __syncthreads();
        for (int b = threadIdx.x; b < NBK; b += 256)
            cnt[b * nCntBlk + blockIdx.x] = hist[b];
        return;
    }

    // stage W as bf16: Wb[j][k] = bf16(W[j][k]); thread t -> row t>>1, half (t&1)*64
    {
        const int j  = threadIdx.x >> 1;
        const int k0 = (threadIdx.x & 1) << 6;
        const float* wr = W + j * DIM + k0;
        u16* wo = Wb + j * TPITCH + k0;
#pragma unroll
        for (int k = 0; k < 64; k += 4) {
            float4 v = *(const float4*)(wr + k);
            ushort4 h;
            h.x = f2bf(v.x); h.y = f2bf(v.y); h.z = f2bf(v.z); h.w = f2bf(v.w);
            *(ushort4*)(wo + k) = h;
        }
    }
    __syncthreads();

    const int wave = threadIdx.x >> 6;
    const int lane = threadIdx.x & 63;
    const int quad = lane >> 4;
    const int l16  = lane & 15;

    const int r0 = (((blockIdx.x - nCntBlk) << 2) + wave) << 4;  // 16 rows/wave
    if (r0 >= n) return;                       // wave-uniform, after all barriers

    const int ar = min(r0 + l16, n - 1);       // A-frag row (clamped on tail)
    const float* arow = A + (size_t)ar * DIM;

    f32x4 acc[8];
#pragma unroll
    for (int c = 0; c < 8; ++c) acc[c] = (f32x4)(0.f);

#pragma unroll
    for (int s = 0; s < 4; ++s) {
        const int koff = (s << 5) + (quad << 3);
        const float4 f0 = *(const float4*)(arow + koff);
        const float4 f1 = *(const float4*)(arow + koff + 4);
        bfrag a;
        a[0] = (short)f2bf(f0.x); a[1] = (short)f2bf(f0.y);
        a[2] = (short)f2bf(f0.z); a[3] = (short)f2bf(f0.w);
        a[4] = (short)f2bf(f1.x); a[5] = (short)f2bf(f1.y);
        a[6] = (short)f2bf(f1.z); a[7] = (short)f2bf(f1.w);
#pragma unroll
        for (int c = 0; c < 8; ++c) {
            const int nn = (c << 4) + l16;     // B col; B[k][n] = W[n][k]
            const bfrag b = *(const bfrag*)(Wb + nn * TPITCH + koff);
            acc[c] = __builtin_amdgcn_mfma_f32_16x16x32_bf16(a, b, acc[c], 0, 0, 0);
        }
    }

    // D[row][col]: row = r0 + quad*4 + r, col = c*16 + l16
#pragma unroll
    for (int r = 0; r < 4; ++r) {
        const int row = r0 + (quad << 2) + r;
        if (row < n) {
            u16* orow = Tb + (size_t)row * DIM + l16;
#pragma unroll
            for (int c = 0; c < 8; ++c)
                orow[c << 4] = f2bf(acc[c][r]);
        }
    }
}

// ---------------------------------------------------------------------------
// K2a: tot[b] = sum of cnt row b (nCntBlk values)
// ---------------------------------------------------------------------------
__global__ __launch_bounds__(256) void k_rowsum(
    const int* __restrict__ cnt, int* __restrict__ tot, int nCntBlk)
{
    __shared__ int red[256];
    const int t = threadIdx.x;
    const int* row = cnt + blockIdx.x * nCntBlk;
    int s = 0;
    for (int i = t; i < nCntBlk; i += 256) s += row[i];
    red[t] = s; __syncthreads();
    for (int o = 128; o; o >>= 1) {
        if (t < o) red[t] += red[t + o];
        __syncthreads();
    }
    if (t == 0) tot[blockIdx.x] = red[0];
}

// ---------------------------------------------------------------------------
// K2b: bucketStart = exclusive scan of tot (NBK <= 512); bucketStart[NBK]=E
// ---------------------------------------------------------------------------
__global__ __launch_bounds__(512) void k_scan_buckets(
    const int* __restrict__ tot, int* __restrict__ bucketStart, int NBK, int E)
{
    __shared__ int sc[512];
    const int t = threadIdx.x;
    const int v = (t < NBK) ? tot[t] : 0;
    sc[t] = v; __syncthreads();
    for (int d = 1; d < 512; d <<= 1) {
        int u = (t >= d) ? sc[t - d] : 0;
        __syncthreads();
        sc[t] += u;
        __syncthreads();
    }
    if (t < NBK) bucketStart[t] = sc[t] - v;
    if (t == 0) bucketStart[NBK] = E;
}

// ---------------------------------------------------------------------------
// K2c: cnt row b -> bucketStart[b] + exclusive scan of the row (in place)
// (requires nCntBlk <= 512)
// ---------------------------------------------------------------------------
__global__ __launch_bounds__(512) void k_rowscan(
    int* __restrict__ cnt, const int* __restrict__ bucketStart, int nCntBlk)
{
    __shared__ int sc[512];
    const int t = threadIdx.x;
    int* row = cnt + blockIdx.x * nCntBlk;
    const int v = (t < nCntBlk) ? row[t] : 0;
    sc[t] = v; __syncthreads();
    for (int d = 1; d < 512; d <<= 1) {
        int u = (t >= d) ? sc[t - d] : 0;
        __syncthreads();
        sc[t] += u;
        __syncthreads();
    }
    if (t < nCntBlk) row[t] = bucketStart[blockIdx.x] + sc[t] - v;
}

// ---------------------------------------------------------------------------
// K3: L1 scatter, LDS-staged. The chunk's edges are bucket-sorted into a
// 32 KB LDS buffer, then flushed with fully coalesced contiguous writes into
// the block-exclusive global runs (positions from the scanned cnt matrix).
// Payload: x = src | (dst&255)<<20, y = w bits.
// ---------------------------------------------------------------------------
__global__ __launch_bounds__(512) void k_scatter(
    const int* __restrict__ src, const int* __restrict__ dst,
    const float* __restrict__ w, const int* __restrict__ cnt,
    const int* __restrict__ bucketStart,
    int2* __restrict__ es1, int E, int nCntBlk, int NBK)
{
    __shared__ int2 buf[CHUNK];          // 32 KB staged payload
    __shared__ u16  bid[CHUNK];          // bucket id per slot (8 KB)
    __shared__ int  gbase[NBK_MAX];      // global run base for this block
    __shared__ int  lbase[NBK_MAX];      // local run base in buf
    __shared__ int  lpos[NBK_MAX];       // running local position
    __shared__ int  sc[512];             // scan scratch

    const int blk  = blockIdx.x;
    const int base = blk * CHUNK;
    const int end  = min(base + CHUNK, E);
    const int len  = end - base;
    const int t    = threadIdx.x;

    // run length per bucket for this block, from the scanned cnt matrix:
    // len(b,blk) = g(b,blk+1) - g(b,blk); last column closes at bucketStart[b+1]
    int mylen = 0;
    if (t < NBK) {
        const int g = cnt[t * nCntBlk + blk];
        gbase[t] = g;
        const int nxt = (blk + 1 < nCntBlk) ? cnt[t * nCntBlk + blk + 1]
                                            : bucketStart[t + 1];
        mylen = nxt - g;
    }
    sc[t] = (t < NBK) ? mylen : 0;
    __syncthreads();
    for (int d = 1; d < 512; d <<= 1) {
        int v = (t >= d) ? sc[t - d] : 0;
        __syncthreads();
        sc[t] += v;
        __syncthreads();
    }
    if (t < NBK) {
        const int ex = sc[t] - mylen;    // exclusive scan -> local base
        lbase[t] = ex;
        lpos[t]  = ex;
    }
    __syncthreads();

    // scatter into LDS (cheap scattered 8B writes stay on-chip)
    for (int i = base + t; i < end; i += 512) {
        const int d   = dst[i];
        const int bkt = d >> BSH;
        const int p   = atomicAdd(&lpos[bkt], 1);
        buf[p] = make_int2(src[i] | ((d & (BSIZE - 1)) << 20),
                           __float_as_int(w[i]));
        bid[p] = (u16)bkt;
    }
    __syncthreads();

    // coalesced flush: consecutive i -> consecutive global addresses per run
    for (int i = t; i < len; i += 512) {
        const int bkt = bid[i];
        es1[gbase[bkt] + (i - lbase[bkt])] = buf[i];
    }
}

// ---------------------------------------------------------------------------
// K4: fine sort within a bucket (256 nodes, block-exclusive ~32 KB window):
// exact CSR off[] + final es2 (dlocal stripped). 512 threads for memory
// parallelism; counters cover the 256 local nodes.
// ---------------------------------------------------------------------------
__global__ __launch_bounds__(512) void k_fine(
    const int2* __restrict__ es1, const int* __restrict__ bucketStart,
    int2* __restrict__ es2, int* __restrict__ off, int n, int NBK)
{
    __shared__ int c[BSIZE];
    __shared__ int cur[BSIZE];
    __shared__ int sc[BSIZE];

    const int b = blockIdx.x;
    const int s = bucketStart[b], e = bucketStart[b + 1];
    const int t = threadIdx.x;

    if (t < BSIZE) c[t] = 0;
    __syncthreads();
    for (int i = s + t; i < e; i += 512)
        atomicAdd(&c[es1[i].x >> 20], 1);
    __syncthreads();

    int myc = 0;
    if (t < BSIZE) { myc = c[t]; sc[t] = myc; }
    __syncthreads();
    for (int d = 1; d < BSIZE; d <<= 1) {
        int v = 0;
        if (t < BSIZE && t >= d) v = sc[t - d];
        __syncthreads();
        if (t < BSIZE) sc[t] += v;
        __syncthreads();
    }
    if (t < BSIZE) {
        const int p = s + sc[t] - myc;        // CSR start for local node t
        cur[t] = p;
        const int v0 = (b << BSH) + t;
        if (v0 < n) off[v0] = p;
    }
    if (b == NBK - 1 && t == 0) off[n] = e;
    __syncthreads();

    for (int i = s + t; i < e; i += 512) {
        const int2 ev = es1[i];
        const int pp = atomicAdd(&cur[ev.x >> 20], 1);
        es2[pp] = make_int2(ev.x & 0xFFFFF, ev.y);
    }
}

// ---------------------------------------------------------------------------
// K5: aggregate, per-node (reverted from edge-streaming which regressed).
// One 64-lane wave per node; lane holds 1 dword (2 bf16) of the row.
// Single fully-predicated unroll-16 chunk loop: 16 T-row gathers in flight
// (overshoot slots clamp to the last edge -> same-address broadcast, weight
// zeroed), 4 independent accumulator pairs. Grid-stride; NT output store.
// ---------------------------------------------------------------------------
__global__ __launch_bounds__(256) void gnn_aggregate(
    const u16* __restrict__ Tb, const int* __restrict__ off,
    const int2* __restrict__ es, float* __restrict__ out, int n)
{
    const int lane = threadIdx.x & 63;
    const int wv   = threadIdx.x >> 6;
    const u32* Tw  = (const u32*)Tb;
    const int step = gridDim.x << 2;

    for (int v = (blockIdx.x << 2) + wv; v < n; v += step) {
        const int b = off[v], e = off[v + 1];

        float ax[4] = {0.f, 0.f, 0.f, 0.f};
        float ay[4] = {0.f, 0.f, 0.f, 0.f};

        if (b < e) {
            const int e1 = e - 1;
            for (int i = b; i < e; i += 16) {
                int2 ev[16];
#pragma unroll
                for (int k = 0; k < 16; ++k)
                    ev[k] = es[min(i + k, e1)];

                u32 tv[16];
#pragma unroll
                for (int k = 0; k < 16; ++k)
                    tv[k] = Tw[(size_t)ev[k].x * 64 + lane];

#pragma unroll
                for (int k = 0; k < 16; ++k) {
                    const float wgt = (i + k < e) ? __int_as_float(ev[k].y) : 0.f;
                    ax[k & 3] += wgt * __uint_as_float(tv[k] << 16);
                    ay[k & 3] += wgt * __uint_as_float(tv[k] & 0xFFFF0000u);
                }
            }
        }

        f32x2 r;
        r[0] = (ax[0] + ax[1]) + (ax[2] + ax[3]);
        r[1] = (ay[0] + ay[1]) + (ay[2] + ay[3]);
        __builtin_nontemporal_store(r, (f32x2*)(out + (size_t)v * DIM + 2 * lane));
    }
}

// ---------------------------------------------------------------------------
extern "C" void kernel_launch(void* const* d_in, const int* in_sizes, int n_in,
                              void* d_out, int out_size, void* d_ws, size_t ws_size,
                              hipStream_t stream)
{
    const float* node_emb = (const float*)d_in[0];
    const float* ew       = (const float*)d_in[1];
    const int*   src      = (const int*)d_in[2];
    const int*   dst      = (const int*)d_in[3];
    const float* W        = (const float*)d_in[4];
    float* out = (float*)d_out;

    const int n = in_sizes[0] / DIM;            // 100000
    const int E = in_sizes[1];                  // 1600000
    const int NBK = (n + BSIZE - 1) >> BSH;     // 391 fine buckets
    const int nCntBlk = (E + CHUNK - 1) / CHUNK;// 391 L1 blocks
    const int M = NBK * nCntBlk;

    // workspace layout (256B-aligned chunks)
    char* ws = (char*)d_ws;
    size_t o = 0;
    u16* Tb = (u16*)(ws + o);  o += (((size_t)n * DIM * sizeof(u16)) + 255) & ~255ULL;
    int* cnt = (int*)(ws + o); o += (((size_t)M * sizeof(int)) + 255) & ~255ULL;
    int* tot = (int*)(ws + o); o += (((size_t)NBK * sizeof(int)) + 255) & ~255ULL;
    int* bucketStart = (int*)(ws + o); o += (((size_t)(NBK + 1) * sizeof(int)) + 255) & ~255ULL;
    int* off = (int*)(ws + o); o += (((size_t)(n + 1) * sizeof(int)) + 255) & ~255ULL;
    int2* es1 = (int2*)(ws + o); o += (((size_t)E * sizeof(int2)) + 255) & ~255ULL;
    int2* es2 = (int2*)(ws + o);

    const int ntiles = (n + 63) >> 6;           // 64 rows per transform block

    // K1: fused L1-count + MFMA transform
    k_count_transform<<<nCntBlk + ntiles, 256, 0, stream>>>(
        node_emb, W, Tb, dst, cnt, n, E, nCntBlk, NBK);

    // K2: parallel scan of the count matrix
    k_rowsum<<<NBK, 256, 0, stream>>>(cnt, tot, nCntBlk);
    k_scan_buckets<<<1, 512, 0, stream>>>(tot, bucketStart, NBK, E);
    k_rowscan<<<NBK, 512, 0, stream>>>(cnt, bucketStart, nCntBlk);

    // K3: LDS-staged L1 scatter with coalesced flush
    k_scatter<<<nCntBlk, 512, 0, stream>>>(src, dst, ew, cnt, bucketStart,
                                           es1, E, nCntBlk, NBK);

    // K4: fine sort within buckets -> exact CSR (off, es2)
    k_fine<<<NBK, 512, 0, stream>>>(es1, bucketStart, es2, off, n, NBK);

    // K5: aggregate (per-node, unroll-16 predicated, grid-stride)
    gnn_aggregate<<<2048, 256, 0, stream>>>(Tb, off, es2, out, n);
}

// Round 5
// 236.006 us; speedup vs baseline: 1.1606x; 1.1606x over previous
//
#include <hip/hip_runtime.h>
#include <cstdint>

typedef unsigned short u16;
typedef unsigned int   u32;

#define DIM     128
#define TPITCH  136          // LDS W row pitch in bf16 (bank-spread)
#define BSH     8            // nodes per fine bucket = 256
#define BSIZE   256
#define NBK_MAX 512          // supports n <= 131072 at BSIZE=256
#define CHUNK   4096         // edges per L1 sort block

__device__ __forceinline__ u16 f2bf(float x) {   // fp32 -> bf16 RTNE
    u32 u = __float_as_uint(x);
    u32 r = u + 0x7FFFu + ((u >> 16) & 1u);
    return (u16)(r >> 16);
}

typedef __attribute__((ext_vector_type(8))) short bfrag;
typedef __attribute__((ext_vector_type(4))) float f32x4;
typedef __attribute__((ext_vector_type(2))) float f32x2;

// ---------------------------------------------------------------------------
// K1 (fat): blocks [0, nCntBlk) do the L1 bucket count; the rest compute
// T(bf16) = A @ W^T with mfma_f32_16x16x32_bf16 (A, W cast to bf16 in-flight).
// Each wave: 16 rows x 128 cols (8 col-tiles, 4 k-steps, 32 MFMA).
// ---------------------------------------------------------------------------
__global__ __launch_bounds__(256) void k_count_transform(
    const float* __restrict__ A, const float* __restrict__ W,
    u16* __restrict__ Tb,
    const int* __restrict__ dst, int* __restrict__ cnt,
    int n, int E, int nCntBlk, int NBK)
{
    __shared__ u16 Wb[DIM * TPITCH];   // 34816 B; count blocks reuse as hist

    if (blockIdx.x < nCntBlk) {
        int* hist = (int*)Wb;
        for (int i = threadIdx.x; i < NBK; i += 256) hist[i] = 0;
        __syncthreads();
        const int base = blockIdx.x * CHUNK;
        const int end  = min(base + CHUNK, E);
        for (int i = base + threadIdx.x; i < end; i += 256)
            atomicAdd(&hist[dst[i] >> BSH], 1);
        __syncthreads();
        for (int b = threadIdx.x; b < NBK; b += 256)
            cnt[b * nCntBlk + blockIdx.x] = hist[b];
        return;
    }

    // stage W as bf16: Wb[j][k] = bf16(W[j][k]); thread t -> row t>>1, half (t&1)*64
    {
        const int j  = threadIdx.x >> 1;
        const int k0 = (threadIdx.x & 1) << 6;
        const float* wr = W + j * DIM + k0;
        u16* wo = Wb + j * TPITCH + k0;
#pragma unroll
        for (int k = 0; k < 64; k += 4) {
            float4 v = *(const float4*)(wr + k);
            ushort4 h;
            h.x = f2bf(v.x); h.y = f2bf(v.y); h.z = f2bf(v.z); h.w = f2bf(v.w);
            *(ushort4*)(wo + k) = h;
        }
    }
    __syncthreads();

    const int wave = threadIdx.x >> 6;
    const int lane = threadIdx.x & 63;
    const int quad = lane >> 4;
    const int l16  = lane & 15;

    const int r0 = (((blockIdx.x - nCntBlk) << 2) + wave) << 4;  // 16 rows/wave
    if (r0 >= n) return;                       // wave-uniform, after all barriers

    const int ar = min(r0 + l16, n - 1);       // A-frag row (clamped on tail)
    const float* arow = A + (size_t)ar * DIM;

    f32x4 acc[8];
#pragma unroll
    for (int c = 0; c < 8; ++c) acc[c] = (f32x4)(0.f);

#pragma unroll
    for (int s = 0; s < 4; ++s) {
        const int koff = (s << 5) + (quad << 3);
        const float4 f0 = *(const float4*)(arow + koff);
        const float4 f1 = *(const float4*)(arow + koff + 4);
        bfrag a;
        a[0] = (short)f2bf(f0.x); a[1] = (short)f2bf(f0.y);
        a[2] = (short)f2bf(f0.z); a[3] = (short)f2bf(f0.w);
        a[4] = (short)f2bf(f1.x); a[5] = (short)f2bf(f1.y);
        a[6] = (short)f2bf(f1.z); a[7] = (short)f2bf(f1.w);
#pragma unroll
        for (int c = 0; c < 8; ++c) {
            const int nn = (c << 4) + l16;     // B col; B[k][n] = W[n][k]
            const bfrag b = *(const bfrag*)(Wb + nn * TPITCH + koff);
            acc[c] = __builtin_amdgcn_mfma_f32_16x16x32_bf16(a, b, acc[c], 0, 0, 0);
        }
    }

    // D[row][col]: row = r0 + quad*4 + r, col = c*16 + l16
#pragma unroll
    for (int r = 0; r < 4; ++r) {
        const int row = r0 + (quad << 2) + r;
        if (row < n) {
            u16* orow = Tb + (size_t)row * DIM + l16;
#pragma unroll
            for (int c = 0; c < 8; ++c)
                orow[c << 4] = f2bf(acc[c][r]);
        }
    }
}

// ---------------------------------------------------------------------------
// K2a: tot[b] = sum of cnt row b (nCntBlk values)
// ---------------------------------------------------------------------------
__global__ __launch_bounds__(256) void k_rowsum(
    const int* __restrict__ cnt, int* __restrict__ tot, int nCntBlk)
{
    __shared__ int red[256];
    const int t = threadIdx.x;
    const int* row = cnt + blockIdx.x * nCntBlk;
    int s = 0;
    for (int i = t; i < nCntBlk; i += 256) s += row[i];
    red[t] = s; __syncthreads();
    for (int o = 128; o; o >>= 1) {
        if (t < o) red[t] += red[t + o];
        __syncthreads();
    }
    if (t == 0) tot[blockIdx.x] = red[0];
}

// ---------------------------------------------------------------------------
// K2bc (fused): every block recomputes bucketStart = exscan(tot) in LDS
// (NBK <= 512 values, cheap); block 0 publishes the global bucketStart
// array; then each block scans its cnt row in place offset by its base.
// Requires NBK <= gridDim == NBK, nCntBlk <= 512, NBK <= 512.
// ---------------------------------------------------------------------------
__global__ __launch_bounds__(512) void k_scan_all(
    const int* __restrict__ tot, int* __restrict__ bucketStart,
    int* __restrict__ cnt, int NBK, int nCntBlk, int E)
{
    __shared__ int sc[512];
    __shared__ int bs;                    // this block's bucket base
    const int t = threadIdx.x;
    const int b = blockIdx.x;

    // pass 1: scan tot
    const int v = (t < NBK) ? tot[t] : 0;
    sc[t] = v; __syncthreads();
    for (int d = 1; d < 512; d <<= 1) {
        int u = (t >= d) ? sc[t - d] : 0;
        __syncthreads();
        sc[t] += u;
        __syncthreads();
    }
    if (t == b) bs = sc[t] - v;           // exclusive prefix at b (b < 512)
    if (b == 0) {
        if (t < NBK) bucketStart[t] = sc[t] - v;
        if (t == 0)  bucketStart[NBK] = E;
    }
    __syncthreads();                      // bs visible; sc reusable

    // pass 2: scan cnt row b, offset by bs
    int* row = cnt + b * nCntBlk;
    const int rv = (t < nCntBlk) ? row[t] : 0;
    sc[t] = rv; __syncthreads();
    for (int d = 1; d < 512; d <<= 1) {
        int u = (t >= d) ? sc[t - d] : 0;
        __syncthreads();
        sc[t] += u;
        __syncthreads();
    }
    if (t < nCntBlk) row[t] = bs + sc[t] - rv;
}

// ---------------------------------------------------------------------------
// K3: L1 scatter, LDS-staged. The chunk's edges are bucket-sorted into a
// 32 KB LDS buffer, then flushed with fully coalesced contiguous writes into
// the block-exclusive global runs (positions from the scanned cnt matrix).
// Payload: x = src | (dst&255)<<20, y = w bits.
// ---------------------------------------------------------------------------
__global__ __launch_bounds__(512) void k_scatter(
    const int* __restrict__ src, const int* __restrict__ dst,
    const float* __restrict__ w, const int* __restrict__ cnt,
    const int* __restrict__ bucketStart,
    int2* __restrict__ es1, int E, int nCntBlk, int NBK)
{
    __shared__ int2 buf[CHUNK];          // 32 KB staged payload
    __shared__ u16  bid[CHUNK];          // bucket id per slot (8 KB)
    __shared__ int  gbase[NBK_MAX];      // global run base for this block
    __shared__ int  lbase[NBK_MAX];      // local run base in buf
    __shared__ int  lpos[NBK_MAX];       // running local position
    __shared__ int  sc[512];             // scan scratch

    const int blk  = blockIdx.x;
    const int base = blk * CHUNK;
    const int end  = min(base + CHUNK, E);
    const int len  = end - base;
    const int t    = threadIdx.x;

    // run length per bucket for this block, from the scanned cnt matrix:
    // len(b,blk) = g(b,blk+1) - g(b,blk); last column closes at bucketStart[b+1]
    int mylen = 0;
    if (t < NBK) {
        const int g = cnt[t * nCntBlk + blk];
        gbase[t] = g;
        const int nxt = (blk + 1 < nCntBlk) ? cnt[t * nCntBlk + blk + 1]
                                            : bucketStart[t + 1];
        mylen = nxt - g;
    }
    sc[t] = (t < NBK) ? mylen : 0;
    __syncthreads();
    for (int d = 1; d < 512; d <<= 1) {
        int v = (t >= d) ? sc[t - d] : 0;
        __syncthreads();
        sc[t] += v;
        __syncthreads();
    }
    if (t < NBK) {
        const int ex = sc[t] - mylen;    // exclusive scan -> local base
        lbase[t] = ex;
        lpos[t]  = ex;
    }
    __syncthreads();

    // scatter into LDS (cheap scattered 8B writes stay on-chip)
    for (int i = base + t; i < end; i += 512) {
        const int d   = dst[i];
        const int bkt = d >> BSH;
        const int p   = atomicAdd(&lpos[bkt], 1);
        buf[p] = make_int2(src[i] | ((d & (BSIZE - 1)) << 20),
                           __float_as_int(w[i]));
        bid[p] = (u16)bkt;
    }
    __syncthreads();

    // coalesced flush: consecutive i -> consecutive global addresses per run
    for (int i = t; i < len; i += 512) {
        const int bkt = bid[i];
        es1[gbase[bkt] + (i - lbase[bkt])] = buf[i];
    }
}

// ---------------------------------------------------------------------------
// K4: fine sort within a bucket (256 nodes, block-exclusive ~32 KB window):
// exact CSR off[] + final es2 (dlocal stripped). 512 threads for memory
// parallelism; counters cover the 256 local nodes.
// ---------------------------------------------------------------------------
__global__ __launch_bounds__(512) void k_fine(
    const int2* __restrict__ es1, const int* __restrict__ bucketStart,
    int2* __restrict__ es2, int* __restrict__ off, int n, int NBK)
{
    __shared__ int c[BSIZE];
    __shared__ int cur[BSIZE];
    __shared__ int sc[BSIZE];

    const int b = blockIdx.x;
    const int s = bucketStart[b], e = bucketStart[b + 1];
    const int t = threadIdx.x;

    if (t < BSIZE) c[t] = 0;
    __syncthreads();
    for (int i = s + t; i < e; i += 512)
        atomicAdd(&c[es1[i].x >> 20], 1);
    __syncthreads();

    int myc = 0;
    if (t < BSIZE) { myc = c[t]; sc[t] = myc; }
    __syncthreads();
    for (int d = 1; d < BSIZE; d <<= 1) {
        int v = 0;
        if (t < BSIZE && t >= d) v = sc[t - d];
        __syncthreads();
        if (t < BSIZE) sc[t] += v;
        __syncthreads();
    }
    if (t < BSIZE) {
        const int p = s + sc[t] - myc;        // CSR start for local node t
        cur[t] = p;
        const int v0 = (b << BSH) + t;
        if (v0 < n) off[v0] = p;
    }
    if (b == NBK - 1 && t == 0) off[n] = e;
    __syncthreads();

    for (int i = s + t; i < e; i += 512) {
        const int2 ev = es1[i];
        const int pp = atomicAdd(&cur[ev.x >> 20], 1);
        es2[pp] = make_int2(ev.x & 0xFFFFF, ev.y);
    }
}

// ---------------------------------------------------------------------------
// K5: aggregate — EXACT round-1 structure (measured 68.5 us; the two
// restructuring attempts regressed to 104/112 us). One 64-lane wave per
// node; lane holds 1 dword (2 bf16); unroll-8 + unroll-4 + scalar tail,
// dual accumulator pairs, grid-stride, nontemporal output store.
// ---------------------------------------------------------------------------
__global__ __launch_bounds__(256) void gnn_aggregate(
    const u16* __restrict__ Tb, const int* __restrict__ off,
    const int2* __restrict__ es, float* __restrict__ out, int n)
{
    const int lane = threadIdx.x & 63;
    const int wv   = threadIdx.x >> 6;
    const u32* Tw  = (const u32*)Tb;
    const int ngrp = (n + 3) >> 2;

    for (int g = blockIdx.x; g < ngrp; g += gridDim.x) {
        const int v = (g << 2) + wv;
        if (v >= n) continue;

        const int b = off[v], e = off[v + 1];
        float ax0 = 0.f, ay0 = 0.f, ax1 = 0.f, ay1 = 0.f;

        int i = b;
        for (; i + 7 < e; i += 8) {
            const int2 e0 = es[i],     e1 = es[i + 1], e2 = es[i + 2], e3 = es[i + 3];
            const int2 e4 = es[i + 4], e5 = es[i + 5], e6 = es[i + 6], e7 = es[i + 7];
            const u32 t0 = Tw[(size_t)e0.x * 64 + lane];
            const u32 t1 = Tw[(size_t)e1.x * 64 + lane];
            const u32 t2 = Tw[(size_t)e2.x * 64 + lane];
            const u32 t3 = Tw[(size_t)e3.x * 64 + lane];
            const u32 t4 = Tw[(size_t)e4.x * 64 + lane];
            const u32 t5 = Tw[(size_t)e5.x * 64 + lane];
            const u32 t6 = Tw[(size_t)e6.x * 64 + lane];
            const u32 t7 = Tw[(size_t)e7.x * 64 + lane];
            const float w0 = __int_as_float(e0.y), w1 = __int_as_float(e1.y);
            const float w2 = __int_as_float(e2.y), w3 = __int_as_float(e3.y);
            const float w4 = __int_as_float(e4.y), w5 = __int_as_float(e5.y);
            const float w6 = __int_as_float(e6.y), w7 = __int_as_float(e7.y);
            ax0 += w0 * __uint_as_float(t0 << 16);
            ay0 += w0 * __uint_as_float(t0 & 0xFFFF0000u);
            ax1 += w1 * __uint_as_float(t1 << 16);
            ay1 += w1 * __uint_as_float(t1 & 0xFFFF0000u);
            ax0 += w2 * __uint_as_float(t2 << 16);
            ay0 += w2 * __uint_as_float(t2 & 0xFFFF0000u);
            ax1 += w3 * __uint_as_float(t3 << 16);
            ay1 += w3 * __uint_as_float(t3 & 0xFFFF0000u);
            ax0 += w4 * __uint_as_float(t4 << 16);
            ay0 += w4 * __uint_as_float(t4 & 0xFFFF0000u);
            ax1 += w5 * __uint_as_float(t5 << 16);
            ay1 += w5 * __uint_as_float(t5 & 0xFFFF0000u);
            ax0 += w6 * __uint_as_float(t6 << 16);
            ay0 += w6 * __uint_as_float(t6 & 0xFFFF0000u);
            ax1 += w7 * __uint_as_float(t7 << 16);
            ay1 += w7 * __uint_as_float(t7 & 0xFFFF0000u);
        }
        for (; i + 3 < e; i += 4) {
            const int2 e0 = es[i], e1 = es[i + 1], e2 = es[i + 2], e3 = es[i + 3];
            const u32 t0 = Tw[(size_t)e0.x * 64 + lane];
            const u32 t1 = Tw[(size_t)e1.x * 64 + lane];
            const u32 t2 = Tw[(size_t)e2.x * 64 + lane];
            const u32 t3 = Tw[(size_t)e3.x * 64 + lane];
            const float w0 = __int_as_float(e0.y), w1 = __int_as_float(e1.y);
            const float w2 = __int_as_float(e2.y), w3 = __int_as_float(e3.y);
            ax0 += w0 * __uint_as_float(t0 << 16);
            ay0 += w0 * __uint_as_float(t0 & 0xFFFF0000u);
            ax1 += w1 * __uint_as_float(t1 << 16);
            ay1 += w1 * __uint_as_float(t1 & 0xFFFF0000u);
            ax0 += w2 * __uint_as_float(t2 << 16);
            ay0 += w2 * __uint_as_float(t2 & 0xFFFF0000u);
            ax1 += w3 * __uint_as_float(t3 << 16);
            ay1 += w3 * __uint_as_float(t3 & 0xFFFF0000u);
        }
        for (; i < e; ++i) {
            const int2 ev = es[i];
            const u32 t = Tw[(size_t)ev.x * 64 + lane];
            const float w0 = __int_as_float(ev.y);
            ax0 += w0 * __uint_as_float(t << 16);
            ay0 += w0 * __uint_as_float(t & 0xFFFF0000u);
        }

        f32x2 r;
        r[0] = ax0 + ax1;
        r[1] = ay0 + ay1;
        __builtin_nontemporal_store(r, (f32x2*)(out + (size_t)v * DIM + 2 * lane));
    }
}

// ---------------------------------------------------------------------------
extern "C" void kernel_launch(void* const* d_in, const int* in_sizes, int n_in,
                              void* d_out, int out_size, void* d_ws, size_t ws_size,
                              hipStream_t stream)
{
    const float* node_emb = (const float*)d_in[0];
    const float* ew       = (const float*)d_in[1];
    const int*   src      = (const int*)d_in[2];
    const int*   dst      = (const int*)d_in[3];
    const float* W        = (const float*)d_in[4];
    float* out = (float*)d_out;

    const int n = in_sizes[0] / DIM;            // 100000
    const int E = in_sizes[1];                  // 1600000
    const int NBK = (n + BSIZE - 1) >> BSH;     // 391 fine buckets
    const int nCntBlk = (E + CHUNK - 1) / CHUNK;// 391 L1 blocks
    const int M = NBK * nCntBlk;

    // workspace layout (256B-aligned chunks)
    char* ws = (char*)d_ws;
    size_t o = 0;
    u16* Tb = (u16*)(ws + o);  o += (((size_t)n * DIM * sizeof(u16)) + 255) & ~255ULL;
    int* cnt = (int*)(ws + o); o += (((size_t)M * sizeof(int)) + 255) & ~255ULL;
    int* tot = (int*)(ws + o); o += (((size_t)NBK * sizeof(int)) + 255) & ~255ULL;
    int* bucketStart = (int*)(ws + o); o += (((size_t)(NBK + 1) * sizeof(int)) + 255) & ~255ULL;
    int* off = (int*)(ws + o); o += (((size_t)(n + 1) * sizeof(int)) + 255) & ~255ULL;
    int2* es1 = (int2*)(ws + o); o += (((size_t)E * sizeof(int2)) + 255) & ~255ULL;
    int2* es2 = (int2*)(ws + o);

    const int ntiles = (n + 63) >> 6;           // 64 rows per transform block

    // K1: fused L1-count + MFMA transform
    k_count_transform<<<nCntBlk + ntiles, 256, 0, stream>>>(
        node_emb, W, Tb, dst, cnt, n, E, nCntBlk, NBK);

    // K2: row sums, then fused bucket-scan + row-scan
    k_rowsum<<<NBK, 256, 0, stream>>>(cnt, tot, nCntBlk);
    k_scan_all<<<NBK, 512, 0, stream>>>(tot, bucketStart, cnt, NBK, nCntBlk, E);

    // K3: LDS-staged L1 scatter with coalesced flush
    k_scatter<<<nCntBlk, 512, 0, stream>>>(src, dst, ew, cnt, bucketStart,
                                           es1, E, nCntBlk, NBK);

    // K4: fine sort within buckets -> exact CSR (off, es2)
    k_fine<<<NBK, 512, 0, stream>>>(es1, bucketStart, es2, off, n, NBK);

    // K5: aggregate (per-node, unroll-8, grid-stride — round-1 measured form)
    gnn_aggregate<<<2048, 256, 0, stream>>>(Tb, off, es2, out, n);
}